// Round 8
// baseline (152.627 us; speedup 1.0000x reference)
//
#include <hip/hip_runtime.h>
#include <hip/hip_bf16.h>

typedef unsigned short u16;
typedef u16   u16x8 __attribute__((ext_vector_type(8)));
typedef short s16x8 __attribute__((ext_vector_type(8)));
typedef float f32x4 __attribute__((ext_vector_type(4)));

__device__ __forceinline__ float bf2f(u16 u) {
    union { unsigned int i; float f; } v; v.i = ((unsigned int)u) << 16; return v.f;
}
__device__ __forceinline__ u16 f2bf(float f) {
    unsigned int x = __float_as_uint(f);
    return (u16)((x + 0x7fffu + ((x >> 16) & 1u)) >> 16);   // RNE
}
__device__ __forceinline__ float ldv(const void* p, size_t i, int f32) {
    return f32 ? ((const float*)p)[i] : bf2f(((const u16*)p)[i]);
}

// ===========================================================================
// GEMM core, BK=64, tile 64 x BN (BN = 64 or 32). 4 waves.
// OUTM=0: C[m][nbase+n] (ldc). OUTM=1: C^T[nbase+n][m] bounce. OUTM=2: NCHW out.
// ===========================================================================
template<int ACT, int OUTM, int OUT_BF16, int BN>
__device__ __forceinline__ void gemm_body(
    u16* __restrict__ smem, int bid,
    const u16* __restrict__ A, const u16* __restrict__ Bt,
    const u16* __restrict__ bias, void* __restrict__ Cv,
    int M, int K, int ldc, int nbase, const int* __restrict__ flag)
{
    constexpr int NF = BN >> 4;
    u16 (*As)[72] = (u16(*)[72])smem;                 // [64][72]
    u16 (*Bs)[72] = (u16(*)[72])(smem + 4608);        // [BN][72]

    const int t    = threadIdx.x;
    const int wv   = t >> 6, lane = t & 63;
    const int fr   = lane & 15, fg = lane >> 4;
    const int tiles_m = M >> 6;
    const int bm = bid % tiles_m, bn = bid / tiles_m;
    const int m0 = bm << 6, n0 = bn * BN;

    f32x4 acc[NF] = {};
    const int srow = t >> 2;
    const int scol = (t & 3) << 4;
    const int brow = (BN == 64) ? srow : (t >> 3);
    const int bcol = (BN == 64) ? scol : ((t & 7) << 3);
    const u16* Ap = A  + (size_t)(m0 + srow) * K + scol;
    const u16* Bp = Bt + (size_t)(n0 + brow) * K + bcol;

    const int ns = K >> 6;
    uint4 av0 = *(const uint4*)Ap, av1 = *(const uint4*)(Ap + 8);
    uint4 bv0 = *(const uint4*)Bp, bv1 = {0,0,0,0};
    if constexpr (BN == 64) bv1 = *(const uint4*)(Bp + 8);
    for (int s = 0; s < ns; ++s) {
        __syncthreads();
        *(uint4*)&As[srow][scol]     = av0;  *(uint4*)&As[srow][scol + 8] = av1;
        *(uint4*)&Bs[brow][bcol]     = bv0;
        if constexpr (BN == 64) *(uint4*)&Bs[brow][bcol + 8] = bv1;
        __syncthreads();
        if (s + 1 < ns) {
            const u16* An = Ap + ((s + 1) << 6);
            const u16* Bn = Bp + ((s + 1) << 6);
            av0 = *(const uint4*)An;  av1 = *(const uint4*)(An + 8);
            bv0 = *(const uint4*)Bn;
            if constexpr (BN == 64) bv1 = *(const uint4*)(Bn + 8);
        }
        union U { uint4 q; s16x8 v; };
        #pragma unroll
        for (int kk = 0; kk < 2; ++kk) {
            U af; af.q = *(const uint4*)&As[(wv << 4) + fr][(kk << 5) + (fg << 3)];
            U bf[NF];
            #pragma unroll
            for (int j = 0; j < NF; ++j)
                bf[j].q = *(const uint4*)&Bs[(j << 4) + fr][(kk << 5) + (fg << 3)];
            #pragma unroll
            for (int j = 0; j < NF; ++j)
                acc[j] = __builtin_amdgcn_mfma_f32_16x16x32_bf16(af.v, bf[j].v, acc[j], 0, 0, 0);
        }
    }

    float vv[NF][4];
    #pragma unroll
    for (int r = 0; r < 4; ++r) {
        float bvv = bf2f(bias[m0 + (wv << 4) + (fg << 2) + r]);
        #pragma unroll
        for (int j = 0; j < NF; ++j) {
            float v = acc[j][r] + bvv;
            if (ACT) v = (v >= 0.f) ? v : 0.1f * v;
            vv[j][r] = v;
        }
    }

    if constexpr (OUTM == 0) {
        #pragma unroll
        for (int j = 0; j < NF; ++j)
            #pragma unroll
            for (int r = 0; r < 4; ++r) {
                size_t idx = (size_t)(m0 + (wv << 4) + (fg << 2) + r) * ldc
                           + (nbase + n0 + (j << 4) + fr);
                if (OUT_BF16) ((u16*)Cv)[idx] = f2bf(vv[j][r]);
                else          ((float*)Cv)[idx] = vv[j][r];
            }
    } else if constexpr (OUTM == 1) {
        __syncthreads();
        u16* bb = smem;                                 // [BN n][72 m]
        #pragma unroll
        for (int j = 0; j < NF; ++j)
            #pragma unroll
            for (int r = 0; r < 4; ++r)
                bb[((j << 4) + fr) * 72 + (wv << 4) + (fg << 2) + r] = f2bf(vv[j][r]);
        __syncthreads();
        if constexpr (BN == 64) {
            int row = t >> 2, seg = (t & 3) << 4;
            const uint4* src = (const uint4*)&bb[row * 72 + seg];
            uint4* dst = (uint4*)((u16*)Cv + (size_t)(nbase + n0 + row) * M + m0 + seg);
            dst[0] = src[0];
            dst[1] = src[1];
        } else {
            int row = t >> 3, seg = (t & 7) << 3;
            const uint4* src = (const uint4*)&bb[row * 72 + seg];
            uint4* dst = (uint4*)((u16*)Cv + (size_t)(nbase + n0 + row) * M + m0 + seg);
            dst[0] = src[0];
        }
    } else {
        __syncthreads();
        constexpr int LDB = BN + 8;
        u16* bb = smem;                                 // [64 m][LDB n]
        #pragma unroll
        for (int j = 0; j < NF; ++j)
            #pragma unroll
            for (int r = 0; r < 4; ++r)
                bb[((wv << 4) + (fg << 2) + r) * LDB + (j << 4) + fr] = f2bf(vv[j][r]);
        __syncthreads();
        int f32o = *flag;
        constexpr int EPT = BN / 4;
        int mrow = t >> 2, seg = (t & 3) * EPT;
        int b = n0 / 1536, hw0 = (n0 % 1536) + seg;
        size_t base = (size_t)(b * 128 + m0 + mrow) * 1536 + hw0;
        if (!f32o) {
            #pragma unroll
            for (int q = 0; q < EPT / 8; ++q)
                *(uint4*)((u16*)Cv + base + q * 8) = *(const uint4*)&bb[mrow * LDB + seg + q * 8];
        } else {
            float* dst = (float*)Cv + base;
            #pragma unroll
            for (int j = 0; j < EPT; ++j) dst[j] = bf2f(bb[mrow * LDB + seg + j]);
        }
    }
}

// ===========================================================================
// Implicit-GEMM 3x3 conv (pad 1), BK=64, tile 64 x BN. POS=1 fuses pos-enc.
// ===========================================================================
template<int CIN, int POS, int BN>
__device__ __forceinline__ void conv_body(
    u16* __restrict__ smem, int bid,
    const u16* __restrict__ A, const u16* __restrict__ X,
    const u16* __restrict__ bias, u16* __restrict__ Cv, int M)
{
    constexpr int NF = BN >> 4;
    u16 (*As)[72] = (u16(*)[72])smem;
    u16 (*Bs)[72] = (u16(*)[72])(smem + 4608);

    constexpr int NK2 = CIN / 64;
    constexpr int TOT = 9 * NK2;

    const int t    = threadIdx.x;
    const int wv   = t >> 6, lane = t & 63;
    const int fr   = lane & 15, fg = lane >> 4;
    const int tiles_m = M >> 6;
    const int bm = bid % tiles_m, bn = bid / tiles_m;
    const int m0 = bm << 6, n0 = bn * BN;

    const int srow = t >> 2;
    const int scol = (t & 3) << 4;
    const int brow = (BN == 64) ? srow : (t >> 3);
    const int bcol = (BN == 64) ? scol : ((t & 7) << 3);
    const int n  = n0 + brow;
    const int hw = n % 1536;
    const int hp = hw / 48, wp = hw % 48;
    const u16* Ar = A + (size_t)(m0 + srow) * (9 * CIN) + scol;

    f32x4 acc[NF] = {};

    auto ld = [&](int s, uint4& a0, uint4& a1, uint4& b0, uint4& b1) {
        int tap = s / NK2, k0 = (s % NK2) << 6;
        int dy = tap / 3 - 1, dx = tap % 3 - 1;
        bool vr = ((unsigned)(hp + dy) < 32u) && ((unsigned)(wp + dx) < 48u);
        const u16* Ap = Ar + tap * CIN + k0;
        a0 = *(const uint4*)Ap;  a1 = *(const uint4*)(Ap + 8);
        if (vr) {
            const u16* Bp = X + (size_t)(n + dy * 48 + dx) * CIN + bcol + k0;
            b0 = *(const uint4*)Bp;
            if constexpr (BN == 64) b1 = *(const uint4*)(Bp + 8);
        } else {
            b0 = uint4{0,0,0,0};  b1 = uint4{0,0,0,0};
        }
    };

    uint4 av0, av1, bv0, bv1;
    ld(0, av0, av1, bv0, bv1);
    for (int s = 0; s < TOT; ++s) {
        __syncthreads();
        *(uint4*)&As[srow][scol]     = av0;  *(uint4*)&As[srow][scol + 8] = av1;
        *(uint4*)&Bs[brow][bcol]     = bv0;
        if constexpr (BN == 64) *(uint4*)&Bs[brow][bcol + 8] = bv1;
        __syncthreads();
        if (s + 1 < TOT) ld(s + 1, av0, av1, bv0, bv1);
        union U { uint4 q; s16x8 v; };
        #pragma unroll
        for (int kk = 0; kk < 2; ++kk) {
            U af; af.q = *(const uint4*)&As[(wv << 4) + fr][(kk << 5) + (fg << 3)];
            U bf[NF];
            #pragma unroll
            for (int j = 0; j < NF; ++j)
                bf[j].q = *(const uint4*)&Bs[(j << 4) + fr][(kk << 5) + (fg << 3)];
            #pragma unroll
            for (int j = 0; j < NF; ++j)
                acc[j] = __builtin_amdgcn_mfma_f32_16x16x32_bf16(af.v, bf[j].v, acc[j], 0, 0, 0);
        }
    }

    float vv[NF][4];
    #pragma unroll
    for (int r = 0; r < 4; ++r) {
        float bvv = bf2f(bias[m0 + (wv << 4) + (fg << 2) + r]);
        #pragma unroll
        for (int j = 0; j < NF; ++j) {
            float v = acc[j][r] + bvv;
            vv[j][r] = (v >= 0.f) ? v : 0.1f * v;
        }
    }

    if (POS) {
        const float TWO_PI = 6.283185307179586f;
        #pragma unroll
        for (int j = 0; j < NF; ++j) {
            int ntok = n0 + (j << 4) + fr;
            int hw2 = ntok % 1536;
            int hp2 = hw2 / 48, wp2 = hw2 % 48;
            float yv = (float)(hp2 + 1) * (TWO_PI / (32.f + 1e-6f));
            float xv = (float)(wp2 + 1) * (TWO_PI / (48.f + 1e-6f));
            #pragma unroll
            for (int r = 0; r < 4; ++r) {
                int d = m0 + (wv << 4) + (fg << 2) + r;
                int mm = (d & 63) >> 1;
                float dim = exp2f((float)mm * (13.287712379549449f / 32.f));
                float val = ((d < 64) ? yv : xv) / dim;
                vv[j][r] += (d & 1) ? cosf(val) : sinf(val);
            }
        }
    }

    __syncthreads();
    u16* bb = smem;                                     // [BN n][72 m]
    #pragma unroll
    for (int j = 0; j < NF; ++j)
        #pragma unroll
        for (int r = 0; r < 4; ++r)
            bb[((j << 4) + fr) * 72 + (wv << 4) + (fg << 2) + r] = f2bf(vv[j][r]);
    __syncthreads();
    if constexpr (BN == 64) {
        int row = t >> 2, seg = (t & 3) << 4;
        const uint4* src = (const uint4*)&bb[row * 72 + seg];
        uint4* dst = (uint4*)(Cv + (size_t)(n0 + row) * M + m0 + seg);
        dst[0] = src[0];
        dst[1] = src[1];
    } else {
        int row = t >> 3, seg = (t & 7) << 3;
        const uint4* src = (const uint4*)&bb[row * 72 + seg];
        uint4* dst = (uint4*)(Cv + (size_t)(n0 + row) * M + m0 + seg);
        dst[0] = src[0];
    }
}

// ---------------------------------------------------------------------------
template<int CIN, int POS, int BN>
__global__ __launch_bounds__(256) void conv_gemm(
    const u16* __restrict__ A, const u16* __restrict__ X,
    const u16* __restrict__ bias, u16* __restrict__ Cv, int M)
{
    __shared__ __align__(16) u16 smem[9216];
    conv_body<CIN, POS, BN>(smem, blockIdx.x, A, X, bias, Cv, M);
}

// fat kernel: value GEMM (960 blocks) || conv1 (384 blocks) — independent work
__global__ __launch_bounds__(256) void val_conv1_k(
    const u16* __restrict__ AVW, const u16* __restrict__ CATT,
    const u16* __restrict__ vb, u16* __restrict__ VAL,
    const u16* __restrict__ AW1, const u16* __restrict__ X0,
    const u16* __restrict__ cb1, u16* __restrict__ CH1)
{
    __shared__ __align__(16) u16 smem[9216];
    int bid = blockIdx.x;
    if (bid < 960) gemm_body<0, 1, 1, 64>(smem, bid, AVW, CATT, vb, VAL, 128, 256, 0, 0, nullptr);
    else           conv_body<128, 0, 64>(smem, bid - 960, AW1, X0, cb1, CH1, 256);
}

// ===========================================================================
// FUSED attention block: per 16-token tile (384 blocks, 256 thr):
//   P1 proj MFMA  PA[tok][192] = APJ*q + BPJ          (LDS)
//   P2 sampling setup + softmax -> (x,y,aw) per sample (LDS)
//   P3 bilinear gather -> S[tok][512] bf16             (LDS)
//   P4 out MFMA   out[tok][128] = AOP*S + OB
// OUTM=0: token-major bf16 dest. OUTM=1: NCHW final (dual dtype via flag).
// ===========================================================================
template<int OUTM>
__global__ __launch_bounds__(256) void attn_fused(
    const u16* __restrict__ QT, const u16* __restrict__ APJ,
    const u16* __restrict__ BPJ, const u16* __restrict__ VAL,
    const u16* __restrict__ AOP, const u16* __restrict__ OB,
    void* __restrict__ OUT, const int* __restrict__ flag)
{
    __shared__ __align__(16) char lds[46144];
    u16*   qs  = (u16*)lds;                              // [16][136] bf16 (bb in P4)
    u16*   Ss  = (u16*)(lds + 4352);                     // [16][520] bf16
    float* PAs = (float*)(lds + 20992);                  // [16][201]
    float* XYs = (float*)(lds + 33856);                  // [16][64][2]
    float* LGs = (float*)(lds + 42048);                  // [16][64] (logit -> aw)

    const int t  = threadIdx.x;
    const int wv = t >> 6, lane = t & 63;
    const int fr = lane & 15, fg = lane >> 4;
    const int bid = blockIdx.x;                          // 384 = 8 XCD * 48
    const int tok0 = ((bid & 7) * 48 + (bid >> 3)) << 4;

    union U { uint4 q; s16x8 v; };

    // ---- P0: stage q tile ----
    {
        int tok = t >> 4, seg = (t & 15) << 3;
        *(uint4*)&qs[tok * 136 + seg] = *(const uint4*)&QT[(size_t)(tok0 + tok) * 128 + seg];
    }
    __syncthreads();

    // ---- P1: proj MFMA (192x16, K=128); wave wv -> m-frags 3wv..3wv+2 ----
    {
        f32x4 pacc[3] = {};
        #pragma unroll
        for (int ks = 0; ks < 4; ++ks) {
            U bf; bf.q = *(const uint4*)&qs[fr * 136 + ks * 32 + (fg << 3)];
            #pragma unroll
            for (int j = 0; j < 3; ++j) {
                int m = ((wv * 3 + j) << 4) + fr;
                U af; af.q = *(const uint4*)&APJ[(size_t)m * 128 + ks * 32 + (fg << 3)];
                pacc[j] = __builtin_amdgcn_mfma_f32_16x16x32_bf16(af.v, bf.v, pacc[j], 0, 0, 0);
            }
        }
        #pragma unroll
        for (int j = 0; j < 3; ++j) {
            int mb = (wv * 3 + j) << 4;
            #pragma unroll
            for (int r = 0; r < 4; ++r) {
                int m = mb + (fg << 2) + r;
                PAs[fr * 201 + m] = pacc[j][r] + bf2f(BPJ[m]);
            }
        }
    }
    __syncthreads();

    // ---- P2a: per-sample (x, y, logit) ----
    #pragma unroll
    for (int i = 0; i < 4; ++i) {
        int slot = t + i * 256;
        int tok = slot >> 6, s = slot & 63;
        int h = s >> 4, l = (s >> 3) & 1, p = s & 7;
        int orow = h * 32 + l * 16 + p * 2;
        int lrow = 128 + h * 16 + l * 8 + p;
        float offx = PAs[tok * 201 + orow];
        float offy = PAs[tok * 201 + orow + 1];
        int gtok = tok0 + tok;
        int hw = gtok % 1536;
        int hp = hw / 48, wp = hw % 48;
        float Wl = l ? 48.f : 96.f, Hl = l ? 32.f : 64.f;
        float locx = (wp + 0.5f) / 48.f + offx / Wl;
        float locy = (hp + 0.5f) / 32.f + offy / Hl;
        XYs[(tok * 64 + s) * 2]     = locx * Wl - 0.5f;
        XYs[(tok * 64 + s) * 2 + 1] = locy * Hl - 0.5f;
        LGs[tok * 64 + s] = PAs[tok * 201 + lrow];
    }
    __syncthreads();

    // ---- P2b: softmax over each (tok, head) group of 16 ----
    float awr[4];
    #pragma unroll
    for (int i = 0; i < 4; ++i) {
        int slot = t + i * 256;
        int tok = slot >> 6, s = slot & 63;
        const float* G = &LGs[tok * 64 + (s & ~15)];
        float mx = -1e30f;
        for (int j2 = 0; j2 < 16; ++j2) mx = fmaxf(mx, G[j2]);
        float sum = 0.f;
        for (int j2 = 0; j2 < 16; ++j2) sum += expf(G[j2] - mx);
        awr[i] = expf(LGs[tok * 64 + s] - mx) / sum;
    }
    __syncthreads();
    #pragma unroll
    for (int i = 0; i < 4; ++i) {
        int slot = t + i * 256;
        LGs[(slot >> 6) * 64 + (slot & 63)] = awr[i];
    }
    __syncthreads();

    // ---- P3: gather (2 rounds x 8 tokens; 32 thr/token: 4h x 8seg16) ----
    {
        const int tokg = t >> 5, sub = t & 31, h = sub >> 3, seg = sub & 7;
        #pragma unroll
        for (int round = 0; round < 2; ++round) {
            int tok = round * 8 + tokg;
            int b = (tok0 + tok) / 1536;
            float acc[16];
            #pragma unroll
            for (int j = 0; j < 16; ++j) acc[j] = 0.f;
            #pragma unroll 2
            for (int s16i = 0; s16i < 16; ++s16i) {
                int s = h * 16 + s16i;
                int l = (s16i >> 3) & 1;
                int iWl = l ? 48 : 96, iHl = l ? 32 : 64;
                int vrow = b * 7680 + (l ? 6144 : 0);
                float x  = XYs[(tok * 64 + s) * 2];
                float y  = XYs[(tok * 64 + s) * 2 + 1];
                float aw = LGs[tok * 64 + s];
                float xf = floorf(x), yf = floorf(y);
                float fx = x - xf, fy = y - yf;
                int ix = (int)xf, iy = (int)yf;
                bool vx0 = (unsigned)ix < (unsigned)iWl, vx1 = (unsigned)(ix + 1) < (unsigned)iWl;
                bool vy0 = (unsigned)iy < (unsigned)iHl, vy1 = (unsigned)(iy + 1) < (unsigned)iHl;
                float w0 = (vx0 && vy0) ? (1.f - fx) * (1.f - fy) * aw : 0.f;
                float w1 = (vx1 && vy0) ? fx * (1.f - fy) * aw : 0.f;
                float w2 = (vx0 && vy1) ? (1.f - fx) * fy * aw : 0.f;
                float w3 = (vx1 && vy1) ? fx * fy * aw : 0.f;
                int i0 = (vx0 && vy0) ? vrow + iy * iWl + ix           : 0;
                int i1 = (vx1 && vy0) ? vrow + iy * iWl + ix + 1       : 0;
                int i2 = (vx0 && vy1) ? vrow + (iy + 1) * iWl + ix     : 0;
                int i3 = (vx1 && vy1) ? vrow + (iy + 1) * iWl + ix + 1 : 0;
                const u16* p0 = VAL + (size_t)i0 * 128 + (seg << 4);
                const u16* p1 = VAL + (size_t)i1 * 128 + (seg << 4);
                const u16* p2 = VAL + (size_t)i2 * 128 + (seg << 4);
                const u16* p3 = VAL + (size_t)i3 * 128 + (seg << 4);
                u16x8 v0a = *(const u16x8*)p0, v0b = *(const u16x8*)(p0 + 8);
                u16x8 v1a = *(const u16x8*)p1, v1b = *(const u16x8*)(p1 + 8);
                u16x8 v2a = *(const u16x8*)p2, v2b = *(const u16x8*)(p2 + 8);
                u16x8 v3a = *(const u16x8*)p3, v3b = *(const u16x8*)(p3 + 8);
                #pragma unroll
                for (int j = 0; j < 8; ++j) {
                    acc[j]     += w0 * bf2f(v0a[j]) + w1 * bf2f(v1a[j])
                                + w2 * bf2f(v2a[j]) + w3 * bf2f(v3a[j]);
                    acc[8 + j] += w0 * bf2f(v0b[j]) + w1 * bf2f(v1b[j])
                                + w2 * bf2f(v2b[j]) + w3 * bf2f(v3b[j]);
                }
            }
            u16x8 o0, o1;
            #pragma unroll
            for (int j = 0; j < 8; ++j) { o0[j] = f2bf(acc[j]); o1[j] = f2bf(acc[8 + j]); }
            u16* sp = &Ss[tok * 520 + (h << 7) + (seg << 4)];
            *(u16x8*)sp = o0;
            *(u16x8*)(sp + 8) = o1;
        }
    }
    __syncthreads();

    // ---- P4: out MFMA (128x16, K=512); wave wv -> m-frags 2wv, 2wv+1 ----
    {
        f32x4 oacc[2] = {};
        for (int ks = 0; ks < 16; ++ks) {
            U bf; bf.q = *(const uint4*)&Ss[fr * 520 + ks * 32 + (fg << 3)];
            #pragma unroll
            for (int j = 0; j < 2; ++j) {
                int m = ((wv * 2 + j) << 4) + fr;
                U af; af.q = *(const uint4*)&AOP[(size_t)m * 512 + ks * 32 + (fg << 3)];
                oacc[j] = __builtin_amdgcn_mfma_f32_16x16x32_bf16(af.v, bf.v, oacc[j], 0, 0, 0);
            }
        }
        #pragma unroll
        for (int j = 0; j < 2; ++j) {
            int mb = (wv * 2 + j) << 4;
            #pragma unroll
            for (int r = 0; r < 4; ++r) {
                int m = mb + (fg << 2) + r;
                qs[fr * 136 + m] = f2bf(oacc[j][r] + bf2f(OB[m]));   // bb[tok][m]
            }
        }
    }
    __syncthreads();

    // ---- P5: store ----
    if constexpr (OUTM == 0) {
        int tok = t >> 4, m0 = (t & 15) << 3;
        *(uint4*)((u16*)OUT + (size_t)(tok0 + tok) * 128 + m0) = *(const uint4*)&qs[tok * 136 + m0];
    } else {
        int f32o = *flag;
        int m = t & 127, grp = t >> 7;
        int b = tok0 / 1536, hw0 = (tok0 % 1536) + (grp << 3);
        size_t base = (size_t)(b * 128 + m) * 1536 + hw0;
        if (!f32o) {
            u16x8 o;
            #pragma unroll
            for (int j = 0; j < 8; ++j) o[j] = qs[((grp << 3) + j) * 136 + m];
            *(u16x8*)((u16*)OUT + base) = o;
        } else {
            #pragma unroll
            for (int j = 0; j < 8; ++j)
                ((float*)OUT)[base + j] = bf2f(qs[((grp << 3) + j) * 136 + m]);
        }
    }
}

// ===========================================================================
// fused prep (unchanged from round 6/7)
// ===========================================================================
struct P21 { const void* p[21]; };
// p[]: 0 cw1,1 cb1,2 cw2,3 cb2,4 cw3,5 cb3,6 vw,7 vb,8 lvl,
//      9 sw0,10 sb0,11 aw0,12 ab0,13 ow0,14 ob0, 15 sw1,16 sb1,17 aw1,18 ab1,19 ow1,20 ob1

__global__ __launch_bounds__(256) void prep_fused(
    P21 a, const void* __restrict__ f00, const void* __restrict__ f01,
    const void* __restrict__ f10, const void* __restrict__ f11,
    int* __restrict__ FLAG,
    u16* AW1, u16* AW2, u16* AW3, u16* AVW,
    u16* APJ0, u16* APJ1, u16* AOP0, u16* AOP1,
    u16* BPJ0, u16* BPJ1, u16* SB,
    u16* CATT, u16* X0)
{
    __shared__ __align__(16) u16 Ts[128 * 66];
    const int t = threadIdx.x;
    unsigned int w = ((const unsigned int*)f00)[t];
    float pa = fabsf(bf2f((u16)(w & 0xFFFFu)));
    int cnt = __syncthreads_count(pa > 1e-6f && pa < 1e4f);
    const int f32 = (cnt < 128);
    const int bid = blockIdx.x;
    if (bid == 0 && t == 0) *FLAG = f32;

    if (bid < 3718) {
        int g = bid * 256 + t;
        if (g < 294912) { int m = g / 1152, rem = g % 1152, tap = rem >> 7, ci = rem & 127;
            AW1[g] = f2bf(ldv(a.p[0], (size_t)m * 1152 + ci * 9 + tap, f32)); return; }
        g -= 294912;
        if (g < 294912) { int m = g / 2304, rem = g % 2304, tap = rem >> 8, ci = rem & 255;
            AW2[g] = f2bf(ldv(a.p[2], (size_t)m * 2304 + ci * 9 + tap, f32)); return; }
        g -= 294912;
        if (g < 147456) { int m = g / 1152, rem = g % 1152, tap = rem >> 7, ci = rem & 127;
            AW3[g] = f2bf(ldv(a.p[4], (size_t)m * 1152 + ci * 9 + tap, f32)); return; }
        g -= 147456;
        if (g < 32768) { AVW[g] = f2bf(ldv(a.p[6], g, f32)); return; }
        g -= 32768;
        if (g < 24576) { int o = g >> 7, d = g & 127;
            APJ0[g] = f2bf(o < 128 ? ldv(a.p[9], d * 128 + o, f32)
                                   : ldv(a.p[11], d * 64 + (o - 128), f32)); return; }
        g -= 24576;
        if (g < 24576) { int o = g >> 7, d = g & 127;
            APJ1[g] = f2bf(o < 128 ? ldv(a.p[15], d * 128 + o, f32)
                                   : ldv(a.p[17], d * 64 + (o - 128), f32)); return; }
        g -= 24576;
        if (g < 65536) { int o = g >> 9, k = g & 511; AOP0[g] = f2bf(ldv(a.p[13], k * 128 + o, f32)); return; }
        g -= 65536;
        if (g < 65536) { int o = g >> 9, k = g & 511; AOP1[g] = f2bf(ldv(a.p[19], k * 128 + o, f32)); return; }
        g -= 65536;
        if (g < 192) { BPJ0[g] = f2bf(g < 128 ? ldv(a.p[10], g, f32) : ldv(a.p[12], g - 128, f32)); return; }
        g -= 192;
        if (g < 192) { BPJ1[g] = f2bf(g < 128 ? ldv(a.p[16], g, f32) : ldv(a.p[18], g - 128, f32)); return; }
        g -= 192;
        if (g < 1152) {
            const int off[8] = {0, 256, 384, 512, 640, 896, 1024, 1152};
            const int src[7] = {1, 3, 5, 7, 8, 14, 20};
            int s = 0;
            #pragma unroll
            for (int i = 1; i < 7; ++i) s += (g >= off[i]);
            SB[g] = f2bf(ldv(a.p[src[s]], g - off[s], f32));
        }
        return;
    }

    const void* src; u16* dst;
    int b, hw0, HW, rowlen, coloff, lvl, addemb;
    if (bid < 4678) {
        int g = bid - 3718;
        int half = g & 1;  g >>= 1;
        b = g / 120;  int tile = g % 120;
        lvl = (tile >= 96) ? 1 : 0;
        int tl = lvl ? tile - 96 : tile;
        hw0 = tl << 6;
        HW = lvl ? 1536 : 6144;
        src = (half == 0) ? (lvl ? f01 : f00) : (lvl ? f11 : f10);
        dst = CATT + (size_t)(b * 7680 + lvl * 6144 + hw0) * 256;
        rowlen = 256; coloff = half << 7; addemb = 1;
    } else {
        int g = bid - 4678;
        b = g / 24;  hw0 = (g % 24) << 6;
        HW = 1536; src = f01;
        dst = X0 + (size_t)(b * 1536 + hw0) * 128;
        rowlen = 128; coloff = 0; lvl = 1; addemb = 0;
    }

    {
        int c = t >> 1, hseg = (t & 1) << 5;
        size_t base = (size_t)(b * 128 + c) * HW + hw0 + hseg;
        u16* dstl = &Ts[c * 66 + hseg];
        if (!f32) {
            const u16* s8 = (const u16*)src + base;
            *(uint4*)(dstl)      = *(const uint4*)(s8);
            *(uint4*)(dstl + 8)  = *(const uint4*)(s8 + 8);
            *(uint4*)(dstl + 16) = *(const uint4*)(s8 + 16);
            *(uint4*)(dstl + 24) = *(const uint4*)(s8 + 24);
        } else {
            const float* sf = (const float*)src + base;
            #pragma unroll
            for (int q = 0; q < 32; ++q) dstl[q] = f2bf(sf[q]);
        }
    }
    __syncthreads();
    {
        int tok = t & 63, cseg = (t >> 6) << 5;
        u16 outv[32];
        #pragma unroll
        for (int j = 0; j < 32; ++j) {
            float x = bf2f(Ts[(cseg + j) * 66 + tok]);
            if (addemb) x += ldv(a.p[8], lvl * 128 + cseg + j, f32);
            outv[j] = f2bf(x);
        }
        u16* drow = dst + (size_t)tok * rowlen + coloff + cseg;
        #pragma unroll
        for (int q = 0; q < 4; ++q)
            *(uint4*)(drow + q * 8) = *(const uint4*)(&outv[q * 8]);
    }
}

// ---------------------------------------------------------------------------
extern "C" void kernel_launch(void* const* d_in, const int* in_sizes, int n_in,
                              void* d_out, int out_size, void* d_ws, size_t ws_size,
                              hipStream_t stream)
{
    (void)in_sizes; (void)n_in; (void)out_size; (void)ws_size;

    char* ws = (char*)d_ws;
    size_t off = 0;
    auto alloc = [&](size_t bytes) { size_t o = off; off += (bytes + 255) & ~(size_t)255; return o; };
    int*   FLAG = (int*)(ws + alloc(256));
    u16*   AW1  = (u16*)(ws + alloc(294912ull * 2));
    u16*   AW2  = (u16*)(ws + alloc(294912ull * 2));
    u16*   AW3  = (u16*)(ws + alloc(147456ull * 2));
    u16*   AVW  = (u16*)(ws + alloc(32768ull * 2));
    u16*   APJ0 = (u16*)(ws + alloc(24576ull * 2));
    u16*   APJ1 = (u16*)(ws + alloc(24576ull * 2));
    u16*   AOP0 = (u16*)(ws + alloc(65536ull * 2));
    u16*   AOP1 = (u16*)(ws + alloc(65536ull * 2));
    u16*   BPJ0 = (u16*)(ws + alloc(512));
    u16*   BPJ1 = (u16*)(ws + alloc(512));
    u16*   SB   = (u16*)(ws + alloc(1152ull * 2));
    u16*   VAL  = (u16*)(ws + alloc(30720ull * 128 * 2));
    u16*   X0   = (u16*)(ws + alloc(6144ull * 128 * 2));
    u16*   CH1  = (u16*)(ws + alloc(6144ull * 256 * 2));
    u16*   CH2  = (u16*)(ws + alloc(6144ull * 128 * 2));
    u16*   QT0  = (u16*)(ws + alloc(6144ull * 128 * 2));
    u16*   QT1  = (u16*)(ws + alloc(6144ull * 128 * 2));
    u16*   CATT = (u16*)(ws + alloc(30720ull * 256 * 2));

    u16* cb1C = SB + 0;   u16* cb2C = SB + 256;  u16* cb3C = SB + 384;
    u16* vbC  = SB + 512;
    u16* ob0C = SB + 896; u16* ob1C = SB + 1024;

    P21 a;
    const int widx[21] = {4,5,6,7,8,9,10,11,12, 13,14,15,16,17,18, 19,20,21,22,23,24};
    for (int i = 0; i < 21; ++i) a.p[i] = d_in[widx[i]];

    // 1. fused prep: weights + CATT + X0 (+FLAG publish)
    prep_fused<<<4774, 256, 0, stream>>>(a, d_in[0], d_in[1], d_in[2], d_in[3], FLAG,
                                         AW1, AW2, AW3, AVW,
                                         APJ0, APJ1, AOP0, AOP1, BPJ0, BPJ1, SB,
                                         CATT, X0);

    // 2. value GEMM || conv1 (fat kernel, independent grids)
    val_conv1_k<<<960 + 384, 256, 0, stream>>>(AVW, CATT, vbC, VAL, AW1, X0, cb1C, CH1);

    // 3. conv2, conv3(+pos)
    conv_gemm<256, 0, 32><<<2 * 192, 256, 0, stream>>>(AW2, CH1, cb2C, CH2, 128);
    conv_gemm<128, 1, 32><<<2 * 192, 256, 0, stream>>>(AW3, CH2, cb3C, QT0, 128);

    // 4. attention block 0 (fused proj+sample+out)
    attn_fused<0><<<384, 256, 0, stream>>>(QT0, APJ0, BPJ0, VAL, AOP0, ob0C, QT1, FLAG);

    // 5. attention block 1 (fused; writes NCHW d_out)
    attn_fused<1><<<384, 256, 0, stream>>>(QT1, APJ1, BPJ1, VAL, AOP1, ob1C, d_out, FLAG);
}

// Round 9
// 144.182 us; speedup vs baseline: 1.0586x; 1.0586x over previous
//
#include <hip/hip_runtime.h>
#include <hip/hip_bf16.h>

typedef unsigned short u16;
typedef u16   u16x8 __attribute__((ext_vector_type(8)));
typedef short s16x8 __attribute__((ext_vector_type(8)));
typedef float f32x4 __attribute__((ext_vector_type(4)));

__device__ __forceinline__ float bf2f(u16 u) {
    union { unsigned int i; float f; } v; v.i = ((unsigned int)u) << 16; return v.f;
}
__device__ __forceinline__ u16 f2bf(float f) {
    unsigned int x = __float_as_uint(f);
    return (u16)((x + 0x7fffu + ((x >> 16) & 1u)) >> 16);   // RNE
}
__device__ __forceinline__ float ldv(const void* p, size_t i, int f32) {
    return f32 ? ((const float*)p)[i] : bf2f(((const u16*)p)[i]);
}

// ===========================================================================
// GEMM core, BK=64, tile 64 x BN (BN = 64 or 32). 4 waves.
// OUTM=0: C[m][nbase+n] (ldc). OUTM=1: C^T[nbase+n][m] bounce. OUTM=2: NCHW out.
// ===========================================================================
template<int ACT, int OUTM, int OUT_BF16, int BN>
__device__ __forceinline__ void gemm_body(
    u16* __restrict__ smem, int bid,
    const u16* __restrict__ A, const u16* __restrict__ Bt,
    const u16* __restrict__ bias, void* __restrict__ Cv,
    int M, int K, int ldc, int nbase, const int* __restrict__ flag)
{
    constexpr int NF = BN >> 4;
    u16 (*As)[72] = (u16(*)[72])smem;                 // [64][72]
    u16 (*Bs)[72] = (u16(*)[72])(smem + 4608);        // [BN][72]

    const int t    = threadIdx.x;
    const int wv   = t >> 6, lane = t & 63;
    const int fr   = lane & 15, fg = lane >> 4;
    const int tiles_m = M >> 6;
    const int bm = bid % tiles_m, bn = bid / tiles_m;
    const int m0 = bm << 6, n0 = bn * BN;

    f32x4 acc[NF] = {};
    const int srow = t >> 2;
    const int scol = (t & 3) << 4;
    const int brow = (BN == 64) ? srow : (t >> 3);
    const int bcol = (BN == 64) ? scol : ((t & 7) << 3);
    const u16* Ap = A  + (size_t)(m0 + srow) * K + scol;
    const u16* Bp = Bt + (size_t)(n0 + brow) * K + bcol;

    const int ns = K >> 6;
    uint4 av0 = *(const uint4*)Ap, av1 = *(const uint4*)(Ap + 8);
    uint4 bv0 = *(const uint4*)Bp, bv1 = {0,0,0,0};
    if constexpr (BN == 64) bv1 = *(const uint4*)(Bp + 8);
    for (int s = 0; s < ns; ++s) {
        __syncthreads();
        *(uint4*)&As[srow][scol]     = av0;  *(uint4*)&As[srow][scol + 8] = av1;
        *(uint4*)&Bs[brow][bcol]     = bv0;
        if constexpr (BN == 64) *(uint4*)&Bs[brow][bcol + 8] = bv1;
        __syncthreads();
        if (s + 1 < ns) {
            const u16* An = Ap + ((s + 1) << 6);
            const u16* Bn = Bp + ((s + 1) << 6);
            av0 = *(const uint4*)An;  av1 = *(const uint4*)(An + 8);
            bv0 = *(const uint4*)Bn;
            if constexpr (BN == 64) bv1 = *(const uint4*)(Bn + 8);
        }
        union U { uint4 q; s16x8 v; };
        #pragma unroll
        for (int kk = 0; kk < 2; ++kk) {
            U af; af.q = *(const uint4*)&As[(wv << 4) + fr][(kk << 5) + (fg << 3)];
            U bf[NF];
            #pragma unroll
            for (int j = 0; j < NF; ++j)
                bf[j].q = *(const uint4*)&Bs[(j << 4) + fr][(kk << 5) + (fg << 3)];
            #pragma unroll
            for (int j = 0; j < NF; ++j)
                acc[j] = __builtin_amdgcn_mfma_f32_16x16x32_bf16(af.v, bf[j].v, acc[j], 0, 0, 0);
        }
    }

    float vv[NF][4];
    #pragma unroll
    for (int r = 0; r < 4; ++r) {
        float bvv = bf2f(bias[m0 + (wv << 4) + (fg << 2) + r]);
        #pragma unroll
        for (int j = 0; j < NF; ++j) {
            float v = acc[j][r] + bvv;
            if (ACT) v = (v >= 0.f) ? v : 0.1f * v;
            vv[j][r] = v;
        }
    }

    if constexpr (OUTM == 0) {
        #pragma unroll
        for (int j = 0; j < NF; ++j)
            #pragma unroll
            for (int r = 0; r < 4; ++r) {
                size_t idx = (size_t)(m0 + (wv << 4) + (fg << 2) + r) * ldc
                           + (nbase + n0 + (j << 4) + fr);
                if (OUT_BF16) ((u16*)Cv)[idx] = f2bf(vv[j][r]);
                else          ((float*)Cv)[idx] = vv[j][r];
            }
    } else if constexpr (OUTM == 1) {
        __syncthreads();
        u16* bb = smem;                                 // [BN n][72 m]
        #pragma unroll
        for (int j = 0; j < NF; ++j)
            #pragma unroll
            for (int r = 0; r < 4; ++r)
                bb[((j << 4) + fr) * 72 + (wv << 4) + (fg << 2) + r] = f2bf(vv[j][r]);
        __syncthreads();
        if constexpr (BN == 64) {
            int row = t >> 2, seg = (t & 3) << 4;
            const uint4* src = (const uint4*)&bb[row * 72 + seg];
            uint4* dst = (uint4*)((u16*)Cv + (size_t)(nbase + n0 + row) * M + m0 + seg);
            dst[0] = src[0];
            dst[1] = src[1];
        } else {
            int row = t >> 3, seg = (t & 7) << 3;
            const uint4* src = (const uint4*)&bb[row * 72 + seg];
            uint4* dst = (uint4*)((u16*)Cv + (size_t)(nbase + n0 + row) * M + m0 + seg);
            dst[0] = src[0];
        }
    } else {
        __syncthreads();
        constexpr int LDB = BN + 8;
        u16* bb = smem;                                 // [64 m][LDB n]
        #pragma unroll
        for (int j = 0; j < NF; ++j)
            #pragma unroll
            for (int r = 0; r < 4; ++r)
                bb[((wv << 4) + (fg << 2) + r) * LDB + (j << 4) + fr] = f2bf(vv[j][r]);
        __syncthreads();
        int f32o = *flag;
        constexpr int EPT = BN / 4;
        int mrow = t >> 2, seg = (t & 3) * EPT;
        int b = n0 / 1536, hw0 = (n0 % 1536) + seg;
        size_t base = (size_t)(b * 128 + m0 + mrow) * 1536 + hw0;
        if (!f32o) {
            #pragma unroll
            for (int q = 0; q < EPT / 8; ++q)
                *(uint4*)((u16*)Cv + base + q * 8) = *(const uint4*)&bb[mrow * LDB + seg + q * 8];
        } else {
            float* dst = (float*)Cv + base;
            #pragma unroll
            for (int j = 0; j < EPT; ++j) dst[j] = bf2f(bb[mrow * LDB + seg + j]);
        }
    }
}

// ===========================================================================
// Implicit-GEMM 3x3 conv (pad 1), BK=64, tile 64 x BN. POS=1 fuses pos-enc.
// ===========================================================================
template<int CIN, int POS, int BN>
__device__ __forceinline__ void conv_body(
    u16* __restrict__ smem, int bid,
    const u16* __restrict__ A, const u16* __restrict__ X,
    const u16* __restrict__ bias, u16* __restrict__ Cv, int M)
{
    constexpr int NF = BN >> 4;
    u16 (*As)[72] = (u16(*)[72])smem;
    u16 (*Bs)[72] = (u16(*)[72])(smem + 4608);

    constexpr int NK2 = CIN / 64;
    constexpr int TOT = 9 * NK2;

    const int t    = threadIdx.x;
    const int wv   = t >> 6, lane = t & 63;
    const int fr   = lane & 15, fg = lane >> 4;
    const int tiles_m = M >> 6;
    const int bm = bid % tiles_m, bn = bid / tiles_m;
    const int m0 = bm << 6, n0 = bn * BN;

    const int srow = t >> 2;
    const int scol = (t & 3) << 4;
    const int brow = (BN == 64) ? srow : (t >> 3);
    const int bcol = (BN == 64) ? scol : ((t & 7) << 3);
    const int n  = n0 + brow;
    const int hw = n % 1536;
    const int hp = hw / 48, wp = hw % 48;
    const u16* Ar = A + (size_t)(m0 + srow) * (9 * CIN) + scol;

    f32x4 acc[NF] = {};

    auto ld = [&](int s, uint4& a0, uint4& a1, uint4& b0, uint4& b1) {
        int tap = s / NK2, k0 = (s % NK2) << 6;
        int dy = tap / 3 - 1, dx = tap % 3 - 1;
        bool vr = ((unsigned)(hp + dy) < 32u) && ((unsigned)(wp + dx) < 48u);
        const u16* Ap = Ar + tap * CIN + k0;
        a0 = *(const uint4*)Ap;  a1 = *(const uint4*)(Ap + 8);
        if (vr) {
            const u16* Bp = X + (size_t)(n + dy * 48 + dx) * CIN + bcol + k0;
            b0 = *(const uint4*)Bp;
            if constexpr (BN == 64) b1 = *(const uint4*)(Bp + 8);
        } else {
            b0 = uint4{0,0,0,0};  b1 = uint4{0,0,0,0};
        }
    };

    uint4 av0, av1, bv0, bv1;
    ld(0, av0, av1, bv0, bv1);
    for (int s = 0; s < TOT; ++s) {
        __syncthreads();
        *(uint4*)&As[srow][scol]     = av0;  *(uint4*)&As[srow][scol + 8] = av1;
        *(uint4*)&Bs[brow][bcol]     = bv0;
        if constexpr (BN == 64) *(uint4*)&Bs[brow][bcol + 8] = bv1;
        __syncthreads();
        if (s + 1 < TOT) ld(s + 1, av0, av1, bv0, bv1);
        union U { uint4 q; s16x8 v; };
        #pragma unroll
        for (int kk = 0; kk < 2; ++kk) {
            U af; af.q = *(const uint4*)&As[(wv << 4) + fr][(kk << 5) + (fg << 3)];
            U bf[NF];
            #pragma unroll
            for (int j = 0; j < NF; ++j)
                bf[j].q = *(const uint4*)&Bs[(j << 4) + fr][(kk << 5) + (fg << 3)];
            #pragma unroll
            for (int j = 0; j < NF; ++j)
                acc[j] = __builtin_amdgcn_mfma_f32_16x16x32_bf16(af.v, bf[j].v, acc[j], 0, 0, 0);
        }
    }

    float vv[NF][4];
    #pragma unroll
    for (int r = 0; r < 4; ++r) {
        float bvv = bf2f(bias[m0 + (wv << 4) + (fg << 2) + r]);
        #pragma unroll
        for (int j = 0; j < NF; ++j) {
            float v = acc[j][r] + bvv;
            vv[j][r] = (v >= 0.f) ? v : 0.1f * v;
        }
    }

    if (POS) {
        const float TWO_PI = 6.283185307179586f;
        #pragma unroll
        for (int j = 0; j < NF; ++j) {
            int ntok = n0 + (j << 4) + fr;
            int hw2 = ntok % 1536;
            int hp2 = hw2 / 48, wp2 = hw2 % 48;
            float yv = (float)(hp2 + 1) * (TWO_PI / (32.f + 1e-6f));
            float xv = (float)(wp2 + 1) * (TWO_PI / (48.f + 1e-6f));
            #pragma unroll
            for (int r = 0; r < 4; ++r) {
                int d = m0 + (wv << 4) + (fg << 2) + r;
                int mm = (d & 63) >> 1;
                float dim = exp2f((float)mm * (13.287712379549449f / 32.f));
                float val = ((d < 64) ? yv : xv) / dim;
                vv[j][r] += (d & 1) ? cosf(val) : sinf(val);
            }
        }
    }

    __syncthreads();
    u16* bb = smem;                                     // [BN n][72 m]
    #pragma unroll
    for (int j = 0; j < NF; ++j)
        #pragma unroll
        for (int r = 0; r < 4; ++r)
            bb[((j << 4) + fr) * 72 + (wv << 4) + (fg << 2) + r] = f2bf(vv[j][r]);
    __syncthreads();
    if constexpr (BN == 64) {
        int row = t >> 2, seg = (t & 3) << 4;
        const uint4* src = (const uint4*)&bb[row * 72 + seg];
        uint4* dst = (uint4*)(Cv + (size_t)(n0 + row) * M + m0 + seg);
        dst[0] = src[0];
        dst[1] = src[1];
    } else {
        int row = t >> 3, seg = (t & 7) << 3;
        const uint4* src = (const uint4*)&bb[row * 72 + seg];
        uint4* dst = (uint4*)(Cv + (size_t)(n0 + row) * M + m0 + seg);
        dst[0] = src[0];
    }
}

// ---------------------------------------------------------------------------
template<int ACT, int OUTM, int OUT_BF16, int BN>
__global__ __launch_bounds__(256) void gemm_kn(
    const u16* __restrict__ A, const u16* __restrict__ Bt,
    const u16* __restrict__ bias, void* __restrict__ Cv,
    int M, int K, int ldc, int nbase, const int* __restrict__ flag)
{
    __shared__ __align__(16) u16 smem[9216];
    gemm_body<ACT, OUTM, OUT_BF16, BN>(smem, blockIdx.x, A, Bt, bias, Cv, M, K, ldc, nbase, flag);
}

template<int CIN, int POS, int BN>
__global__ __launch_bounds__(256) void conv_gemm(
    const u16* __restrict__ A, const u16* __restrict__ X,
    const u16* __restrict__ bias, u16* __restrict__ Cv, int M)
{
    __shared__ __align__(16) u16 smem[9216];
    conv_body<CIN, POS, BN>(smem, blockIdx.x, A, X, bias, Cv, M);
}

// fat kernel: value GEMM (960 blocks) || conv1 (384 blocks) — independent work
__global__ __launch_bounds__(256) void val_conv1_k(
    const u16* __restrict__ AVW, const u16* __restrict__ CATT,
    const u16* __restrict__ vb, u16* __restrict__ VAL,
    const u16* __restrict__ AW1, const u16* __restrict__ X0,
    const u16* __restrict__ cb1, u16* __restrict__ CH1)
{
    __shared__ __align__(16) u16 smem[9216];
    int bid = blockIdx.x;
    if (bid < 960) gemm_body<0, 1, 1, 64>(smem, bid, AVW, CATT, vb, VAL, 128, 256, 0, 0, nullptr);
    else           conv_body<128, 0, 64>(smem, bid - 960, AW1, X0, cb1, CH1, 256);
}

// ===========================================================================
// msda_proj: proj MFMA + sampling-softmax + gather for 8 tokens/block.
// 768 blocks x 256 thr (~17KB LDS -> deep co-residency keeps gather TLP).
//   P1 proj MFMA  PA[8][192] = APJ*q + BPJ    (16-col fragment, 8 cols dead)
//   P2 per-sample (x,y) + softmax -> aw        (LDS)
//   P3 bilinear gather -> S[tok][512] global (round-7 access pattern)
// ===========================================================================
__global__ __launch_bounds__(256) void msda_proj(
    const u16* __restrict__ QT, const u16* __restrict__ APJ,
    const u16* __restrict__ BPJ, const u16* __restrict__ VAL,
    u16* __restrict__ S)
{
    __shared__ __align__(16) u16 qs[16 * 136];           // 16 rows, 8 real
    __shared__ float PAs[8][201];
    __shared__ float XYs[8][64][2];
    __shared__ float LGs[8][64];

    const int t  = threadIdx.x;
    const int wv = t >> 6, lane = t & 63;
    const int fr = lane & 15, fg = lane >> 4;
    const int bid = blockIdx.x;                          // 768 = 8 XCD * 96
    const int tok0 = ((bid & 7) * 96 + (bid >> 3)) << 3; // 8 tokens/tile

    union U { uint4 q; s16x8 v; };

    // ---- P0: stage q tile (rows 8..15 zeroed) ----
    {
        int tok = t >> 4, seg = (t & 15) << 3;
        uint4 v = {0, 0, 0, 0};
        if (tok < 8) v = *(const uint4*)&QT[(size_t)(tok0 + tok) * 128 + seg];
        *(uint4*)&qs[tok * 136 + seg] = v;
    }
    __syncthreads();

    // ---- P1: proj MFMA (192 x 8, K=128); wave wv -> m-frags 3wv..3wv+2 ----
    {
        f32x4 pacc[3] = {};
        #pragma unroll
        for (int ks = 0; ks < 4; ++ks) {
            U bf; bf.q = *(const uint4*)&qs[fr * 136 + ks * 32 + (fg << 3)];
            #pragma unroll
            for (int j = 0; j < 3; ++j) {
                int m = ((wv * 3 + j) << 4) + fr;
                U af; af.q = *(const uint4*)&APJ[(size_t)m * 128 + ks * 32 + (fg << 3)];
                pacc[j] = __builtin_amdgcn_mfma_f32_16x16x32_bf16(af.v, bf.v, pacc[j], 0, 0, 0);
            }
        }
        if (fr < 8) {
            #pragma unroll
            for (int j = 0; j < 3; ++j) {
                int mb = (wv * 3 + j) << 4;
                #pragma unroll
                for (int r = 0; r < 4; ++r) {
                    int m = mb + (fg << 2) + r;
                    PAs[fr][m] = pacc[j][r] + bf2f(BPJ[m]);
                }
            }
        }
    }
    __syncthreads();

    // ---- P2a: per-sample (x, y, logit);  512 slots = 2 per thread ----
    #pragma unroll
    for (int i = 0; i < 2; ++i) {
        int slot = t + i * 256;
        int tok = slot >> 6, s = slot & 63;
        int h = s >> 4, l = (s >> 3) & 1, p = s & 7;
        int orow = h * 32 + l * 16 + p * 2;
        float offx = PAs[tok][orow];
        float offy = PAs[tok][orow + 1];
        int gtok = tok0 + tok;
        int hw = gtok % 1536;
        int hp = hw / 48, wp = hw % 48;
        float Wl = l ? 48.f : 96.f, Hl = l ? 32.f : 64.f;
        float locx = (wp + 0.5f) / 48.f + offx / Wl;
        float locy = (hp + 0.5f) / 32.f + offy / Hl;
        XYs[tok][s][0] = locx * Wl - 0.5f;
        XYs[tok][s][1] = locy * Hl - 0.5f;
        LGs[tok][s] = PAs[tok][128 + h * 16 + l * 8 + p];
    }
    __syncthreads();

    // ---- P2b: softmax over each (tok, head) group of 16 ----
    float awr[2];
    #pragma unroll
    for (int i = 0; i < 2; ++i) {
        int slot = t + i * 256;
        int tok = slot >> 6, s = slot & 63;
        const float* G = &LGs[tok][s & ~15];
        float mx = -1e30f;
        for (int j2 = 0; j2 < 16; ++j2) mx = fmaxf(mx, G[j2]);
        float sum = 0.f;
        for (int j2 = 0; j2 < 16; ++j2) sum += expf(G[j2] - mx);
        awr[i] = expf(LGs[tok][s] - mx) / sum;
    }
    __syncthreads();
    #pragma unroll
    for (int i = 0; i < 2; ++i) {
        int slot = t + i * 256;
        LGs[slot >> 6][slot & 63] = awr[i];
    }
    __syncthreads();

    // ---- P3: gather (8 tokens; 32 thr/token: 4h x 8seg16) -> S global ----
    {
        const int tok = t >> 5, sub = t & 31, h = sub >> 3, seg = sub & 7;
        int b = (tok0 + tok) / 1536;
        float acc[16];
        #pragma unroll
        for (int j = 0; j < 16; ++j) acc[j] = 0.f;
        #pragma unroll 2
        for (int s16i = 0; s16i < 16; ++s16i) {
            int s = h * 16 + s16i;
            int l = (s16i >> 3) & 1;
            int iWl = l ? 48 : 96, iHl = l ? 32 : 64;
            int vrow = b * 7680 + (l ? 6144 : 0);
            float x  = XYs[tok][s][0];
            float y  = XYs[tok][s][1];
            float aw = LGs[tok][s];
            float xf = floorf(x), yf = floorf(y);
            float fx = x - xf, fy = y - yf;
            int ix = (int)xf, iy = (int)yf;
            bool vx0 = (unsigned)ix < (unsigned)iWl, vx1 = (unsigned)(ix + 1) < (unsigned)iWl;
            bool vy0 = (unsigned)iy < (unsigned)iHl, vy1 = (unsigned)(iy + 1) < (unsigned)iHl;
            float w0 = (vx0 && vy0) ? (1.f - fx) * (1.f - fy) * aw : 0.f;
            float w1 = (vx1 && vy0) ? fx * (1.f - fy) * aw : 0.f;
            float w2 = (vx0 && vy1) ? (1.f - fx) * fy * aw : 0.f;
            float w3 = (vx1 && vy1) ? fx * fy * aw : 0.f;
            int i0 = (vx0 && vy0) ? vrow + iy * iWl + ix           : 0;
            int i1 = (vx1 && vy0) ? vrow + iy * iWl + ix + 1       : 0;
            int i2 = (vx0 && vy1) ? vrow + (iy + 1) * iWl + ix     : 0;
            int i3 = (vx1 && vy1) ? vrow + (iy + 1) * iWl + ix + 1 : 0;
            const u16* p0 = VAL + (size_t)i0 * 128 + (seg << 4);
            const u16* p1 = VAL + (size_t)i1 * 128 + (seg << 4);
            const u16* p2 = VAL + (size_t)i2 * 128 + (seg << 4);
            const u16* p3 = VAL + (size_t)i3 * 128 + (seg << 4);
            u16x8 v0a = *(const u16x8*)p0, v0b = *(const u16x8*)(p0 + 8);
            u16x8 v1a = *(const u16x8*)p1, v1b = *(const u16x8*)(p1 + 8);
            u16x8 v2a = *(const u16x8*)p2, v2b = *(const u16x8*)(p2 + 8);
            u16x8 v3a = *(const u16x8*)p3, v3b = *(const u16x8*)(p3 + 8);
            #pragma unroll
            for (int j = 0; j < 8; ++j) {
                acc[j]     += w0 * bf2f(v0a[j]) + w1 * bf2f(v1a[j])
                            + w2 * bf2f(v2a[j]) + w3 * bf2f(v3a[j]);
                acc[8 + j] += w0 * bf2f(v0b[j]) + w1 * bf2f(v1b[j])
                            + w2 * bf2f(v2b[j]) + w3 * bf2f(v3b[j]);
            }
        }
        u16x8 o0, o1;
        #pragma unroll
        for (int j = 0; j < 8; ++j) { o0[j] = f2bf(acc[j]); o1[j] = f2bf(acc[8 + j]); }
        u16* sp = S + (size_t)(tok0 + tok) * 512 + (h << 7) + (seg << 4);
        *(u16x8*)sp = o0;
        *(u16x8*)(sp + 8) = o1;
    }
}

// ===========================================================================
// fused prep (unchanged from round 6/7)
// ===========================================================================
struct P21 { const void* p[21]; };
// p[]: 0 cw1,1 cb1,2 cw2,3 cb2,4 cw3,5 cb3,6 vw,7 vb,8 lvl,
//      9 sw0,10 sb0,11 aw0,12 ab0,13 ow0,14 ob0, 15 sw1,16 sb1,17 aw1,18 ab1,19 ow1,20 ob1

__global__ __launch_bounds__(256) void prep_fused(
    P21 a, const void* __restrict__ f00, const void* __restrict__ f01,
    const void* __restrict__ f10, const void* __restrict__ f11,
    int* __restrict__ FLAG,
    u16* AW1, u16* AW2, u16* AW3, u16* AVW,
    u16* APJ0, u16* APJ1, u16* AOP0, u16* AOP1,
    u16* BPJ0, u16* BPJ1, u16* SB,
    u16* CATT, u16* X0)
{
    __shared__ __align__(16) u16 Ts[128 * 66];
    const int t = threadIdx.x;
    unsigned int w = ((const unsigned int*)f00)[t];
    float pa = fabsf(bf2f((u16)(w & 0xFFFFu)));
    int cnt = __syncthreads_count(pa > 1e-6f && pa < 1e4f);
    const int f32 = (cnt < 128);
    const int bid = blockIdx.x;
    if (bid == 0 && t == 0) *FLAG = f32;

    if (bid < 3718) {
        int g = bid * 256 + t;
        if (g < 294912) { int m = g / 1152, rem = g % 1152, tap = rem >> 7, ci = rem & 127;
            AW1[g] = f2bf(ldv(a.p[0], (size_t)m * 1152 + ci * 9 + tap, f32)); return; }
        g -= 294912;
        if (g < 294912) { int m = g / 2304, rem = g % 2304, tap = rem >> 8, ci = rem & 255;
            AW2[g] = f2bf(ldv(a.p[2], (size_t)m * 2304 + ci * 9 + tap, f32)); return; }
        g -= 294912;
        if (g < 147456) { int m = g / 1152, rem = g % 1152, tap = rem >> 7, ci = rem & 127;
            AW3[g] = f2bf(ldv(a.p[4], (size_t)m * 1152 + ci * 9 + tap, f32)); return; }
        g -= 147456;
        if (g < 32768) { AVW[g] = f2bf(ldv(a.p[6], g, f32)); return; }
        g -= 32768;
        if (g < 24576) { int o = g >> 7, d = g & 127;
            APJ0[g] = f2bf(o < 128 ? ldv(a.p[9], d * 128 + o, f32)
                                   : ldv(a.p[11], d * 64 + (o - 128), f32)); return; }
        g -= 24576;
        if (g < 24576) { int o = g >> 7, d = g & 127;
            APJ1[g] = f2bf(o < 128 ? ldv(a.p[15], d * 128 + o, f32)
                                   : ldv(a.p[17], d * 64 + (o - 128), f32)); return; }
        g -= 24576;
        if (g < 65536) { int o = g >> 9, k = g & 511; AOP0[g] = f2bf(ldv(a.p[13], k * 128 + o, f32)); return; }
        g -= 65536;
        if (g < 65536) { int o = g >> 9, k = g & 511; AOP1[g] = f2bf(ldv(a.p[19], k * 128 + o, f32)); return; }
        g -= 65536;
        if (g < 192) { BPJ0[g] = f2bf(g < 128 ? ldv(a.p[10], g, f32) : ldv(a.p[12], g - 128, f32)); return; }
        g -= 192;
        if (g < 192) { BPJ1[g] = f2bf(g < 128 ? ldv(a.p[16], g, f32) : ldv(a.p[18], g - 128, f32)); return; }
        g -= 192;
        if (g < 1152) {
            const int off[8] = {0, 256, 384, 512, 640, 896, 1024, 1152};
            const int src[7] = {1, 3, 5, 7, 8, 14, 20};
            int s = 0;
            #pragma unroll
            for (int i = 1; i < 7; ++i) s += (g >= off[i]);
            SB[g] = f2bf(ldv(a.p[src[s]], g - off[s], f32));
        }
        return;
    }

    const void* src; u16* dst;
    int b, hw0, HW, rowlen, coloff, lvl, addemb;
    if (bid < 4678) {
        int g = bid - 3718;
        int half = g & 1;  g >>= 1;
        b = g / 120;  int tile = g % 120;
        lvl = (tile >= 96) ? 1 : 0;
        int tl = lvl ? tile - 96 : tile;
        hw0 = tl << 6;
        HW = lvl ? 1536 : 6144;
        src = (half == 0) ? (lvl ? f01 : f00) : (lvl ? f11 : f10);
        dst = CATT + (size_t)(b * 7680 + lvl * 6144 + hw0) * 256;
        rowlen = 256; coloff = half << 7; addemb = 1;
    } else {
        int g = bid - 4678;
        b = g / 24;  hw0 = (g % 24) << 6;
        HW = 1536; src = f01;
        dst = X0 + (size_t)(b * 1536 + hw0) * 128;
        rowlen = 128; coloff = 0; lvl = 1; addemb = 0;
    }

    {
        int c = t >> 1, hseg = (t & 1) << 5;
        size_t base = (size_t)(b * 128 + c) * HW + hw0 + hseg;
        u16* dstl = &Ts[c * 66 + hseg];
        if (!f32) {
            const u16* s8 = (const u16*)src + base;
            *(uint4*)(dstl)      = *(const uint4*)(s8);
            *(uint4*)(dstl + 8)  = *(const uint4*)(s8 + 8);
            *(uint4*)(dstl + 16) = *(const uint4*)(s8 + 16);
            *(uint4*)(dstl + 24) = *(const uint4*)(s8 + 24);
        } else {
            const float* sf = (const float*)src + base;
            #pragma unroll
            for (int q = 0; q < 32; ++q) dstl[q] = f2bf(sf[q]);
        }
    }
    __syncthreads();
    {
        int tok = t & 63, cseg = (t >> 6) << 5;
        u16 outv[32];
        #pragma unroll
        for (int j = 0; j < 32; ++j) {
            float x = bf2f(Ts[(cseg + j) * 66 + tok]);
            if (addemb) x += ldv(a.p[8], lvl * 128 + cseg + j, f32);
            outv[j] = f2bf(x);
        }
        u16* drow = dst + (size_t)tok * rowlen + coloff + cseg;
        #pragma unroll
        for (int q = 0; q < 4; ++q)
            *(uint4*)(drow + q * 8) = *(const uint4*)(&outv[q * 8]);
    }
}

// ---------------------------------------------------------------------------
extern "C" void kernel_launch(void* const* d_in, const int* in_sizes, int n_in,
                              void* d_out, int out_size, void* d_ws, size_t ws_size,
                              hipStream_t stream)
{
    (void)in_sizes; (void)n_in; (void)out_size; (void)ws_size;

    char* ws = (char*)d_ws;
    size_t off = 0;
    auto alloc = [&](size_t bytes) { size_t o = off; off += (bytes + 255) & ~(size_t)255; return o; };
    int*   FLAG = (int*)(ws + alloc(256));
    u16*   AW1  = (u16*)(ws + alloc(294912ull * 2));
    u16*   AW2  = (u16*)(ws + alloc(294912ull * 2));
    u16*   AW3  = (u16*)(ws + alloc(147456ull * 2));
    u16*   AVW  = (u16*)(ws + alloc(32768ull * 2));
    u16*   APJ0 = (u16*)(ws + alloc(24576ull * 2));
    u16*   APJ1 = (u16*)(ws + alloc(24576ull * 2));
    u16*   AOP0 = (u16*)(ws + alloc(65536ull * 2));
    u16*   AOP1 = (u16*)(ws + alloc(65536ull * 2));
    u16*   BPJ0 = (u16*)(ws + alloc(512));
    u16*   BPJ1 = (u16*)(ws + alloc(512));
    u16*   SB   = (u16*)(ws + alloc(1152ull * 2));
    u16*   VAL  = (u16*)(ws + alloc(30720ull * 128 * 2));
    u16*   X0   = (u16*)(ws + alloc(6144ull * 128 * 2));
    u16*   CH1  = (u16*)(ws + alloc(6144ull * 256 * 2));
    u16*   CH2  = (u16*)(ws + alloc(6144ull * 128 * 2));
    u16*   QT0  = (u16*)(ws + alloc(6144ull * 128 * 2));
    u16*   QT1  = (u16*)(ws + alloc(6144ull * 128 * 2));
    char*  R    = ws + alloc(30720ull * 256 * 2);          // union: CATT | S
    u16*   CATT = (u16*)R;
    u16*   S    = (u16*)R;

    u16* cb1C = SB + 0;   u16* cb2C = SB + 256;  u16* cb3C = SB + 384;
    u16* vbC  = SB + 512;
    u16* ob0C = SB + 896; u16* ob1C = SB + 1024;

    P21 a;
    const int widx[21] = {4,5,6,7,8,9,10,11,12, 13,14,15,16,17,18, 19,20,21,22,23,24};
    for (int i = 0; i < 21; ++i) a.p[i] = d_in[widx[i]];

    // 1. fused prep: weights + CATT + X0 (+FLAG publish)
    prep_fused<<<4774, 256, 0, stream>>>(a, d_in[0], d_in[1], d_in[2], d_in[3], FLAG,
                                         AW1, AW2, AW3, AVW,
                                         APJ0, APJ1, AOP0, AOP1, BPJ0, BPJ1, SB,
                                         CATT, X0);

    // 2. value GEMM || conv1 (fat kernel, independent grids)
    val_conv1_k<<<960 + 384, 256, 0, stream>>>(AVW, CATT, vbC, VAL, AW1, X0, cb1C, CH1);

    // 3. conv2, conv3(+pos)
    conv_gemm<256, 0, 32><<<2 * 192, 256, 0, stream>>>(AW2, CH1, cb2C, CH2, 128);
    conv_gemm<128, 1, 32><<<2 * 192, 256, 0, stream>>>(AW3, CH2, cb3C, QT0, 128);

    // 4. attention block 0: fused proj+sample, then out GEMM
    msda_proj<<<768, 256, 0, stream>>>(QT0, APJ0, BPJ0, VAL, S);
    gemm_kn<0, 1, 1, 32><<<2 * 192, 256, 0, stream>>>(AOP0, S, ob0C, QT1, 128, 512, 0, 0, FLAG);

    // 5. attention block 1 (out GEMM writes NCHW d_out)
    msda_proj<<<768, 256, 0, stream>>>(QT1, APJ1, BPJ1, VAL, S);
    gemm_kn<0, 2, 1, 32><<<2 * 192, 256, 0, stream>>>(AOP1, S, ob1C, d_out, 128, 512, 0, 0, FLAG);
}